// Round 17
// baseline (740.298 us; speedup 1.0000x reference)
//
#include <hip/hip_runtime.h>
#include <hip/hip_bf16.h>
#include <math.h>

// HGNN forward, MI355X — round 17: identical to round 16 (infra flake re-run).
// Quarter-feature-split gathers: working set per pass = 100K x 16 bf16 =
// 3.2MB < 4MB per-XCD L2. (r11 half-split at 6.4MB missed L2 -> null; r15
// deeper MLP traded VGPR/occupancy -> null. Remaining lever: L2 residency.)
// Gather kernels: pure gather (no LDS), 32B rows, 8 edge slots/instr,
// r13-style index-prefetch loop (low VGPR). M1/M2: r11-proven epilogues.
// attn == softmax over size-1 axis == 1.0 exactly, so W1/b1/W2/b2 are unused.

#define HID   64
#define RB    128
#define CHUNK 4096

__device__ __forceinline__ float bflo(unsigned u) { return __int_as_float((int)(u << 16)); }
__device__ __forceinline__ float bfhi(unsigned u) { return __int_as_float((int)(u & 0xFFFF0000u)); }
__device__ __forceinline__ float bf2f(ushort v) { return __int_as_float((int)(((unsigned)v) << 16)); }
__device__ __forceinline__ ushort f2bf(float f) {
    unsigned u = __float_as_uint(f);
    unsigned r = u + 0x7FFFu + ((u >> 16) & 1u);
    return (ushort)(r >> 16);
}
__device__ __forceinline__ unsigned pack2(float lo, float hi) {
    return (unsigned)f2bf(lo) | ((unsigned)f2bf(hi) << 16);
}

// ---------------- zero rows (row N of every quarter plane) + sentinels ----------------
__global__ void zeroRow(unsigned* __restrict__ ghq, unsigned* __restrict__ s1q,
                        float* __restrict__ dinv0, float* __restrict__ dinv1, int N) {
    int tid = threadIdx.x;
    size_t P8 = (size_t)(N + 1) * 8;          // u32 per plane
    if (tid < 32) {
        int p = tid >> 3, wd = tid & 7;
        ghq[(size_t)p * P8 + (size_t)N * 8 + wd] = 0u;
        s1q[(size_t)p * P8 + (size_t)N * 8 + wd] = 0u;
    }
    if (tid == 0) { dinv0[N] = 0.0f; dinv1[N] = 0.0f; }
}

// ---------------- bucket histogram ----------------
__global__ void histA(const int* __restrict__ dst0, const int* __restrict__ dst1,
                      int E, unsigned M, int* __restrict__ bcnt) {
    __shared__ int h[2 * RB];
    for (int i = threadIdx.x; i < 2 * RB; i += blockDim.x) h[i] = 0;
    __syncthreads();
    int stride = gridDim.x * blockDim.x;
    for (int i = blockIdx.x * blockDim.x + threadIdx.x; i < E; i += stride) {
        atomicAdd(&h[__umulhi((unsigned)dst0[i], M)], 1);
        atomicAdd(&h[RB + __umulhi((unsigned)dst1[i], M)], 1);
    }
    __syncthreads();
    for (int i = threadIdx.x; i < 2 * RB; i += blockDim.x)
        if (h[i]) atomicAdd(&bcnt[i], h[i]);
}

// ---------------- bucket scan ----------------
__global__ void scanA(const int* __restrict__ bcnt, int* __restrict__ bbase,
                      int* __restrict__ bcur) {
    __shared__ int t[2 * RB];
    int tid = threadIdx.x;
    int orig = bcnt[tid];
    t[tid] = orig;
    __syncthreads();
    int list = tid >> 7, r = tid & (RB - 1);
    for (int o = 1; o < RB; o <<= 1) {
        int u = (r >= o) ? t[tid - o] : 0;
        __syncthreads();
        t[tid] += u;
        __syncthreads();
    }
    int incl = t[tid];
    int excl = incl - orig;
    bbase[list * (RB + 1) + r] = excl;
    bcur[tid] = excl;
    if (r == RB - 1) bbase[list * (RB + 1) + RB] = incl;
}

// ------- partition: chunked counting sort -> bucket-ordered packed arena -------
__global__ void __launch_bounds__(256) partB(const int* __restrict__ e0,
                                             const int* __restrict__ e1,
                                             int E, int BW, unsigned M,
                                             int* __restrict__ bcur_all,
                                             unsigned* __restrict__ arena_all) {
    __shared__ int hist[RB], scn[RB], lbase[RB], cur[RB], gbase[RB];
    __shared__ uint2 buf[CHUNK];
    int half = gridDim.x >> 1;
    int list = (blockIdx.x >= half) ? 1 : 0;
    const int* src = list ? e1 : e0;
    const int* dst = src + E;
    int* bcur = bcur_all + list * RB;
    unsigned* arena = arena_all + (size_t)list * E;
    int blk = blockIdx.x - list * half;
    int tid = threadIdx.x;

    for (int c0 = blk * CHUNK; c0 < E; c0 += half * CHUNK) {
        int cn = min(CHUNK, E - c0);
        for (int i = tid; i < RB; i += 256) hist[i] = 0;
        __syncthreads();
        unsigned ls[16], ld[16];
        #pragma unroll
        for (int k = 0; k < 16; ++k) {
            int j = k * 256 + tid;
            ld[k] = 0xFFFFFFFFu; ls[k] = 0;
            if (j < cn) {
                ls[k] = (unsigned)src[c0 + j];
                ld[k] = (unsigned)dst[c0 + j];
                atomicAdd(&hist[__umulhi(ld[k], M)], 1);
            }
        }
        __syncthreads();
        if (tid < RB) scn[tid] = hist[tid];
        __syncthreads();
        for (int o = 1; o < RB; o <<= 1) {
            int u = (tid < RB && tid >= o) ? scn[tid - o] : 0;
            __syncthreads();
            if (tid < RB) scn[tid] += u;
            __syncthreads();
        }
        if (tid < RB) {
            int ex = scn[tid] - hist[tid];
            lbase[tid] = ex;
            cur[tid]   = ex;
            gbase[tid] = hist[tid] ? atomicAdd(&bcur[tid], hist[tid]) : 0;
        }
        __syncthreads();
        #pragma unroll
        for (int k = 0; k < 16; ++k) {
            if (ld[k] != 0xFFFFFFFFu) {
                int b = __umulhi(ld[k], M);
                int slot = atomicAdd(&cur[b], 1);
                buf[slot] = make_uint2(ls[k], ld[k]);
            }
        }
        __syncthreads();
        for (int i = tid; i < cn; i += 256) {
            uint2 p = buf[i];
            int b = __umulhi(p.y, M);
            arena[gbase[b] + (i - lbase[b])] = (p.x << 10) | (p.y - (unsigned)(b * BW));
        }
        __syncthreads();
    }
}

// ------- per-bucket padded CSR build (pad to 16; off = base | niter<<25) -------
__global__ void __launch_bounds__(1024) buildC(const unsigned* __restrict__ arena_all,
                                               const int* __restrict__ bbase,
                                               int E, int N, int BW,
                                               int* __restrict__ csr0p, int* __restrict__ csr1p,
                                               unsigned* __restrict__ offp0, unsigned* __restrict__ offp1,
                                               float* __restrict__ dinv0, float* __restrict__ dinv1) {
    __shared__ int degl[800], scn[800], cur[800];
    int list = blockIdx.x >> 7, rb = blockIdx.x & (RB - 1);
    const unsigned* arena = arena_all + (size_t)list * E;
    int* csr = list ? csr1p : csr0p;
    unsigned* offp = list ? offp1 : offp0;
    float* dinv = list ? dinv1 : dinv0;
    int base = bbase[list * (RB + 1) + rb];
    int end  = bbase[list * (RB + 1) + rb + 1];
    int csrb = base + 16 * BW * rb;
    int nbase = rb * BW;
    int nn = min(BW, N - nbase);
    if (nn <= 0) return;
    int tid = threadIdx.x;
    for (int i = tid; i < nn; i += 1024) degl[i] = 0;
    __syncthreads();
    for (int j = base + tid; j < end; j += 1024)
        atomicAdd(&degl[arena[j] & 1023u], 1);
    __syncthreads();
    int d = (tid < nn) ? degl[tid] : 0;
    int dp = d ? ((d + 15) & ~15) : 0;
    if (tid < nn) scn[tid] = dp;
    __syncthreads();
    for (int o = 1; o < nn; o <<= 1) {
        int u = (tid < nn && tid >= o) ? scn[tid - o] : 0;
        __syncthreads();
        if (tid < nn) scn[tid] += u;
        __syncthreads();
    }
    if (tid < nn) {
        int ex = scn[tid] - dp;
        cur[tid] = ex;
        offp[nbase + tid] = (unsigned)(csrb + ex) | ((unsigned)(dp >> 4) << 25);
        dinv[nbase + tid] = rsqrtf((float)(d + 1));
        for (int j = ex + d; j < ex + dp; ++j) csr[csrb + j] = N;   // pads -> zero row
    }
    __syncthreads();
    for (int j = base + tid; j < end; j += 1024) {
        unsigned p = arena[j];
        int loc = atomicAdd(&cur[p & 1023u], 1);
        csr[csrb + loc] = (int)(p >> 10);
    }
}

// ------ input projection: write quarter-split planes; unroll 16 ------
__global__ void input_proj(const float* __restrict__ x, const int* __restrict__ types,
                           const float* __restrict__ W_in, const float* __restrict__ b_in,
                           ushort* __restrict__ ghq, int N, int F) {
    __shared__ float xs[4 * 128];
    int tid = threadIdx.x;
    int w = tid >> 6, h = tid & 63;
    int n0 = blockIdx.x * 4;
    for (int i = tid; i < 4 * F; i += 256) {
        int nn = n0 + i / F;
        xs[i] = (nn < N) ? x[(size_t)nn * F + (i % F)] : 0.0f;
    }
    __syncthreads();
    int n = n0 + w;
    if (n >= N) return;
    int t = types[n];
    const float* W = W_in + (size_t)t * F * HID;
    float acc = b_in[t * HID + h];
    const float* xr = xs + w * F;
    #pragma unroll 16
    for (int f = 0; f < F; ++f)
        acc = fmaf(xr[f], W[(size_t)f * HID + h], acc);
    size_t P1 = (size_t)(N + 1) * 16;
    ghq[(size_t)(h >> 4) * P1 + (size_t)n * 16 + (h & 15)] = f2bf(acc);
}

// weighted quarter-gather: 32B rows, 8 slots/instr, 16 edges/iter, idx prefetch
__device__ __forceinline__ void gatherQW(const unsigned* __restrict__ GH,
                                         const float* __restrict__ dv,
                                         const int* __restrict__ csr,
                                         unsigned wword, int q, int fl, float a[2]) {
    int base = (int)(wword & 0x1FFFFFFu);
    int it = (int)(wword >> 25);
    if (it == 0) return;
    const int* cp = csr + base;
    int ia = cp[q], ib = cp[8 + q];
    while (true) {
        unsigned va = GH[(size_t)ia * 8 + fl];
        unsigned vb = GH[(size_t)ib * 8 + fl];
        float wa = dv[ia], wb = dv[ib];
        --it; cp += 16;
        int na = 0, nb = 0;
        if (it > 0) { na = cp[q]; nb = cp[8 + q]; }
        a[0] = fmaf(bflo(va), wa, a[0]);
        a[1] = fmaf(bfhi(va), wa, a[1]);
        a[0] = fmaf(bflo(vb), wb, a[0]);
        a[1] = fmaf(bfhi(vb), wb, a[1]);
        if (it == 0) break;
        ia = na; ib = nb;
    }
}

// unweighted quarter-gather (source pre-scaled)
__device__ __forceinline__ void gatherQU(const unsigned* __restrict__ GH,
                                         const int* __restrict__ csr,
                                         unsigned wword, int q, int fl, float a[2]) {
    int base = (int)(wword & 0x1FFFFFFu);
    int it = (int)(wword >> 25);
    if (it == 0) return;
    const int* cp = csr + base;
    int ia = cp[q], ib = cp[8 + q];
    while (true) {
        unsigned va = GH[(size_t)ia * 8 + fl];
        unsigned vb = GH[(size_t)ib * 8 + fl];
        --it; cp += 16;
        int na = 0, nb = 0;
        if (it > 0) { na = cp[q]; nb = cp[8 + q]; }
        a[0] += bflo(va) + bflo(vb);
        a[1] += bfhi(va) + bfhi(vb);
        if (it == 0) break;
        ia = na; ib = nb;
    }
}

// ---- G1: one quarter plane, BOTH lists, weighted -> aq0, aq1 (no LDS) ----
__global__ void __launch_bounds__(256) gatherQ1(
        const ushort* __restrict__ ghp,
        const unsigned* __restrict__ offp0, const int* __restrict__ csr0p,
        const float* __restrict__ dinv0,
        const unsigned* __restrict__ offp1, const int* __restrict__ csr1p,
        const float* __restrict__ dinv1,
        ushort* __restrict__ a0p, ushort* __restrict__ a1p, int N) {
    int w = threadIdx.x >> 6, lane = threadIdx.x & 63;
    int q = lane >> 3, fl = lane & 7;
    int n = blockIdx.x * 4 + w;
    if (n >= N) return;
    const unsigned* GH = (const unsigned*)ghp;
    float d0 = dinv0[n], d1 = dinv1[n];
    float a0[2] = {0, 0}, a1[2] = {0, 0};
    if (q == 0) {                              // self term
        unsigned sv = GH[(size_t)n * 8 + fl];
        float f0 = bflo(sv), f1 = bfhi(sv);
        a0[0] = f0 * d0; a0[1] = f1 * d0;
        a1[0] = f0 * d1; a1[1] = f1 * d1;
    }
    gatherQW(GH, dinv0, csr0p, offp0[n], q, fl, a0);
    gatherQW(GH, dinv1, csr1p, offp1[n], q, fl, a1);
    #pragma unroll
    for (int k = 0; k < 2; ++k) {
        a0[k] += __shfl_xor(a0[k], 8, 64);
        a0[k] += __shfl_xor(a0[k], 16, 64);
        a0[k] += __shfl_xor(a0[k], 32, 64);
        a1[k] += __shfl_xor(a1[k], 8, 64);
        a1[k] += __shfl_xor(a1[k], 16, 64);
        a1[k] += __shfl_xor(a1[k], 32, 64);
        a0[k] *= d0;
        a1[k] *= d1;
    }
    if (q == 0) {
        ((unsigned*)a0p)[(size_t)n * 8 + fl] = pack2(a0[0], a0[1]);
        ((unsigned*)a1p)[(size_t)n * 8 + fl] = pack2(a1[0], a1[1]);
    }
}

// ---- G2: one quarter plane of s1 (pre-scaled), list 0 only -> bq ----
__global__ void __launch_bounds__(256) gatherQ2(
        const ushort* __restrict__ s1p,
        const unsigned* __restrict__ offp0, const int* __restrict__ csr0p,
        const float* __restrict__ dinv0,
        ushort* __restrict__ bp, int N) {
    int w = threadIdx.x >> 6, lane = threadIdx.x & 63;
    int q = lane >> 3, fl = lane & 7;
    int n = blockIdx.x * 4 + w;
    if (n >= N) return;
    const unsigned* S = (const unsigned*)s1p;
    float d0 = dinv0[n];
    float a[2] = {0, 0};
    if (q == 0) {                              // self (rows pre-scaled by d0[src])
        unsigned sv = S[(size_t)n * 8 + fl];
        a[0] = bflo(sv); a[1] = bfhi(sv);
    }
    gatherQU(S, csr0p, offp0[n], q, fl, a);
    #pragma unroll
    for (int k = 0; k < 2; ++k) {
        a[k] += __shfl_xor(a[k], 8, 64);
        a[k] += __shfl_xor(a[k], 16, 64);
        a[k] += __shfl_xor(a[k], 32, 64);
        a[k] *= d0;
    }
    if (q == 0)
        ((unsigned*)bp)[(size_t)n * 8 + fl] = pack2(a[0], a[1]);
}

// ---- M1: s1 = max(a0@W0+b0, a1@W1+b1); write s1*d0 quarter-split ----
__global__ void __launch_bounds__(512) matM1(
        const ushort* __restrict__ aq0, const ushort* __restrict__ aq1,
        const float* __restrict__ dinv0,
        const float* __restrict__ W_conv, const float* __restrict__ b_conv,
        ushort* __restrict__ s1q, int N) {
    __shared__ float Ws[2 * HID * HID];        // 32 KB fp32 W0,W1
    __shared__ float ag0[8][HID], ag1[8][HID];
    int tid = threadIdx.x;
    for (int i = tid; i < 2 * HID * HID; i += 512) Ws[i] = W_conv[i];
    __syncthreads();
    int w = tid >> 6, h = tid & 63;
    int n = blockIdx.x * 8 + w;
    if (n >= N) return;
    size_t PN = (size_t)N * 16;
    size_t P1 = (size_t)(N + 1) * 16;
    size_t idx = (size_t)(h >> 4) * PN + (size_t)n * 16 + (h & 15);
    ag0[w][h] = bf2f(aq0[idx]);
    ag1[w][h] = bf2f(aq1[idx]);
    float m0 = b_conv[h];
    float m1 = b_conv[HID + h];
    #pragma unroll 8
    for (int k = 0; k < HID; ++k) {
        m0 = fmaf(ag0[w][k], Ws[k * HID + h], m0);
        m1 = fmaf(ag1[w][k], Ws[HID * HID + k * HID + h], m1);
    }
    float s1 = fmaxf(m0, m1) * dinv0[n];       // pre-scale for layer-2 gather
    s1q[(size_t)(h >> 4) * P1 + (size_t)n * 16 + (h & 15)] = f2bf(s1);
}

// ---- M2: s2 = max(a0@W2+b2, b@W3c+b3c); LN; gelu; @W3+b3 -> out ----
__global__ void __launch_bounds__(512) matM2(
        const ushort* __restrict__ aq0, const ushort* __restrict__ bq,
        const float* __restrict__ W_conv, const float* __restrict__ b_conv,
        const float* __restrict__ W3, const float* __restrict__ b3,
        float* __restrict__ out, int N) {
    __shared__ float Ws[2 * HID * HID];        // 32 KB fp32 W2,W3c
    __shared__ float W3s[HID * 8];
    __shared__ float ag[8][HID], bg[8][HID], gs[8][HID];
    int tid = threadIdx.x;
    for (int i = tid; i < 2 * HID * HID; i += 512) Ws[i] = W_conv[2 * HID * HID + i];
    if (tid < HID * 8) W3s[tid] = W3[tid];
    __syncthreads();
    int w = tid >> 6, h = tid & 63;
    int n = blockIdx.x * 8 + w;
    if (n >= N) return;
    size_t PN = (size_t)N * 16;
    size_t idx = (size_t)(h >> 4) * PN + (size_t)n * 16 + (h & 15);
    ag[w][h] = bf2f(aq0[idx]);
    bg[w][h] = bf2f(bq[idx]);
    float m2 = b_conv[2 * HID + h];
    float m3 = b_conv[3 * HID + h];
    #pragma unroll 8
    for (int k = 0; k < HID; ++k) {
        m2 = fmaf(ag[w][k], Ws[k * HID + h], m2);
        m3 = fmaf(bg[w][k], Ws[HID * HID + k * HID + h], m3);
    }
    float s2 = fmaxf(m2, m3);
    float sum = s2;
    #pragma unroll
    for (int off = 32; off; off >>= 1) sum += __shfl_xor(sum, off, 64);
    float mu = sum * (1.0f / 64.0f);
    float dv = s2 - mu;
    float v = dv * dv;
    #pragma unroll
    for (int off = 32; off; off >>= 1) v += __shfl_xor(v, off, 64);
    float xn = dv * rsqrtf(v * (1.0f / 64.0f) + 1e-5f);
    float g = 0.5f * xn * (1.0f + erff(xn * 0.70710678118654752f));
    gs[w][h] = g;
    if (h < 8) {
        float acc = b3[h];
        #pragma unroll 8
        for (int k = 0; k < HID; ++k)
            acc = fmaf(gs[w][k], W3s[k * 8 + h], acc);
        out[(size_t)n * 8 + h] = acc;
    }
}

extern "C" void kernel_launch(void* const* d_in, const int* in_sizes, int n_in,
                              void* d_out, int out_size, void* d_ws, size_t ws_size,
                              hipStream_t stream) {
    const float* x          = (const float*)d_in[0];
    const int*   node_types = (const int*)d_in[1];
    const int*   e0         = (const int*)d_in[2];
    const int*   e1         = (const int*)d_in[3];
    const float* W_in       = (const float*)d_in[4];
    const float* b_in       = (const float*)d_in[5];
    const float* W_conv     = (const float*)d_in[6];
    const float* b_conv     = (const float*)d_in[7];
    const float* W3         = (const float*)d_in[12];
    const float* b3         = (const float*)d_in[13];
    float* out = (float*)d_out;

    int N = in_sizes[1];
    int F = in_sizes[0] / N;        // 128
    int E = in_sizes[2] / 2;        // 1.6M
    int BW = (N + RB - 1) / RB;     // 782
    unsigned M = (unsigned)(0x100000000ULL / (unsigned long long)BW) + 1u;
    size_t EP = (size_t)E + 16 * (size_t)BW * RB + 64;

    // workspace layout (u32 units)
    unsigned* ws32 = (unsigned*)d_ws;
    int*      bcnt  = (int*)ws32;                        // 2*RB
    int*      bbase = bcnt + 2 * RB;                     // 2*(RB+1)
    int*      bcur  = bbase + 2 * (RB + 1);              // 2*RB (+6 pad)
    unsigned* offp0 = (unsigned*)(bcur + 2 * RB + 6);    // N+1
    unsigned* offp1 = offp0 + (N + 1);                   // N+1
    float*    dinv0 = (float*)(offp1 + (N + 1));         // N+1
    float*    dinv1 = dinv0 + (N + 1);                   // N+1
    int*      csr0p = (int*)(dinv1 + (N + 1));           // EP
    int*      csr1p = csr0p + EP;                        // EP
    ushort*   ghq   = (ushort*)(csr1p + EP);             // 4 planes x (N+1)*16 bf16
    ushort*   s1q   = ghq + (size_t)4 * (N + 1) * 16;    // 4 planes x (N+1)*16 bf16
    ushort*   aq0   = s1q + (size_t)4 * (N + 1) * 16;    // 4 planes x N*16 bf16
    ushort*   aq1   = aq0 + (size_t)4 * N * 16;          // 4 planes x N*16 bf16
    ushort*   bq    = aq1 + (size_t)4 * N * 16;          // 4 planes x N*16 bf16
    unsigned* arena = (unsigned*)aq0;                    // 2E u32, dead after buildC

    size_t P1 = (size_t)(N + 1) * 16;   // ushorts per ghq/s1q plane
    size_t PN = (size_t)N * 16;         // ushorts per aq/bq plane

    (void)hipMemsetAsync(bcnt, 0, 2 * RB * sizeof(int), stream);
    zeroRow<<<1, 64, 0, stream>>>((unsigned*)ghq, (unsigned*)s1q, dinv0, dinv1, N);
    histA<<<1024, 256, 0, stream>>>(e0 + E, e1 + E, E, M, bcnt);
    scanA<<<1, 256, 0, stream>>>(bcnt, bbase, bcur);
    partB<<<256, 256, 0, stream>>>(e0, e1, E, BW, M, bcur, arena);
    buildC<<<2 * RB, 1024, 0, stream>>>(arena, bbase, E, N, BW,
                                        csr0p, csr1p, offp0, offp1, dinv0, dinv1);
    input_proj<<<(N + 3) / 4, 256, 0, stream>>>(x, node_types, W_in, b_in, ghq, N, F);
    for (int qt = 0; qt < 4; ++qt)
        gatherQ1<<<(N + 3) / 4, 256, 0, stream>>>(ghq + qt * P1, offp0, csr0p, dinv0,
                                                  offp1, csr1p, dinv1,
                                                  aq0 + qt * PN, aq1 + qt * PN, N);
    matM1<<<(N + 7) / 8, 512, 0, stream>>>(aq0, aq1, dinv0, W_conv, b_conv, s1q, N);
    for (int qt = 0; qt < 4; ++qt)
        gatherQ2<<<(N + 3) / 4, 256, 0, stream>>>(s1q + qt * P1, offp0, csr0p, dinv0,
                                                  bq + qt * PN, N);
    matM2<<<(N + 7) / 8, 512, 0, stream>>>(aq0, bq, W_conv, b_conv, W3, b3, out, N);
}

// Round 18
// 455.425 us; speedup vs baseline: 1.6255x; 1.6255x over previous
//
#include <hip/hip_runtime.h>
#include <hip/hip_bf16.h>
#include <math.h>

// HGNN forward, MI355X — round 18: revert to round-13 structure (best: 484us)
// + dual-node gatherL2 (2 independent 4-deep chains/wave = 8 rows in flight,
// mirroring gatherL1's proven shape; r15's register-pipeline alternative lost
// to VGPR/occupancy; r17 proved quarter-split gains are eaten by csr streams).
// attn == softmax over size-1 axis == 1.0 exactly, so W1/b1/W2/b2 are unused.

#define HID   64
#define RB    128
#define CHUNK 4096

__device__ __forceinline__ float bflo(unsigned u) { return __int_as_float((int)(u << 16)); }
__device__ __forceinline__ float bfhi(unsigned u) { return __int_as_float((int)(u & 0xFFFF0000u)); }
__device__ __forceinline__ float bf2f(ushort v) { return __int_as_float((int)(((unsigned)v) << 16)); }
__device__ __forceinline__ ushort f2bf(float f) {
    unsigned u = __float_as_uint(f);
    unsigned r = u + 0x7FFFu + ((u >> 16) & 1u);
    return (ushort)(r >> 16);
}
__device__ __forceinline__ void addw(float a[4], uint2 v, float wgt) {
    a[0] = fmaf(bflo(v.x), wgt, a[0]);
    a[1] = fmaf(bfhi(v.x), wgt, a[1]);
    a[2] = fmaf(bflo(v.y), wgt, a[2]);
    a[3] = fmaf(bfhi(v.y), wgt, a[3]);
}
__device__ __forceinline__ void addu(float a[4], uint2 v) {
    a[0] += bflo(v.x); a[1] += bfhi(v.x);
    a[2] += bflo(v.y); a[3] += bfhi(v.y);
}

// ---------------- zero rows + dinv sentinels ----------------
__global__ void zeroRow(unsigned* __restrict__ ghz, unsigned* __restrict__ s1z,
                        float* __restrict__ dinv0, float* __restrict__ dinv1, int N) {
    int tid = threadIdx.x;
    if (tid < 32) { ghz[tid] = 0u; s1z[tid] = 0u; }
    if (tid == 0) { dinv0[N] = 0.0f; dinv1[N] = 0.0f; }
}

// ---------------- bucket histogram ----------------
__global__ void histA(const int* __restrict__ dst0, const int* __restrict__ dst1,
                      int E, unsigned M, int* __restrict__ bcnt) {
    __shared__ int h[2 * RB];
    for (int i = threadIdx.x; i < 2 * RB; i += blockDim.x) h[i] = 0;
    __syncthreads();
    int stride = gridDim.x * blockDim.x;
    for (int i = blockIdx.x * blockDim.x + threadIdx.x; i < E; i += stride) {
        atomicAdd(&h[__umulhi((unsigned)dst0[i], M)], 1);
        atomicAdd(&h[RB + __umulhi((unsigned)dst1[i], M)], 1);
    }
    __syncthreads();
    for (int i = threadIdx.x; i < 2 * RB; i += blockDim.x)
        if (h[i]) atomicAdd(&bcnt[i], h[i]);
}

// ---------------- bucket scan ----------------
__global__ void scanA(const int* __restrict__ bcnt, int* __restrict__ bbase,
                      int* __restrict__ bcur) {
    __shared__ int t[2 * RB];
    int tid = threadIdx.x;
    int orig = bcnt[tid];
    t[tid] = orig;
    __syncthreads();
    int list = tid >> 7, r = tid & (RB - 1);
    for (int o = 1; o < RB; o <<= 1) {
        int u = (r >= o) ? t[tid - o] : 0;
        __syncthreads();
        t[tid] += u;
        __syncthreads();
    }
    int incl = t[tid];
    int excl = incl - orig;
    bbase[list * (RB + 1) + r] = excl;
    bcur[tid] = excl;
    if (r == RB - 1) bbase[list * (RB + 1) + RB] = incl;
}

// ------- partition: chunked counting sort -> bucket-ordered packed arena -------
__global__ void __launch_bounds__(256) partB(const int* __restrict__ e0,
                                             const int* __restrict__ e1,
                                             int E, int BW, unsigned M,
                                             int* __restrict__ bcur_all,
                                             unsigned* __restrict__ arena_all) {
    __shared__ int hist[RB], scn[RB], lbase[RB], cur[RB], gbase[RB];
    __shared__ uint2 buf[CHUNK];
    int half = gridDim.x >> 1;
    int list = (blockIdx.x >= half) ? 1 : 0;
    const int* src = list ? e1 : e0;
    const int* dst = src + E;
    int* bcur = bcur_all + list * RB;
    unsigned* arena = arena_all + (size_t)list * E;
    int blk = blockIdx.x - list * half;
    int tid = threadIdx.x;

    for (int c0 = blk * CHUNK; c0 < E; c0 += half * CHUNK) {
        int cn = min(CHUNK, E - c0);
        for (int i = tid; i < RB; i += 256) hist[i] = 0;
        __syncthreads();
        unsigned ls[16], ld[16];
        #pragma unroll
        for (int k = 0; k < 16; ++k) {
            int j = k * 256 + tid;
            ld[k] = 0xFFFFFFFFu; ls[k] = 0;
            if (j < cn) {
                ls[k] = (unsigned)src[c0 + j];
                ld[k] = (unsigned)dst[c0 + j];
                atomicAdd(&hist[__umulhi(ld[k], M)], 1);
            }
        }
        __syncthreads();
        if (tid < RB) scn[tid] = hist[tid];
        __syncthreads();
        for (int o = 1; o < RB; o <<= 1) {
            int u = (tid < RB && tid >= o) ? scn[tid - o] : 0;
            __syncthreads();
            if (tid < RB) scn[tid] += u;
            __syncthreads();
        }
        if (tid < RB) {
            int ex = scn[tid] - hist[tid];
            lbase[tid] = ex;
            cur[tid]   = ex;
            gbase[tid] = hist[tid] ? atomicAdd(&bcur[tid], hist[tid]) : 0;
        }
        __syncthreads();
        #pragma unroll
        for (int k = 0; k < 16; ++k) {
            if (ld[k] != 0xFFFFFFFFu) {
                int b = __umulhi(ld[k], M);
                int slot = atomicAdd(&cur[b], 1);
                buf[slot] = make_uint2(ls[k], ld[k]);
            }
        }
        __syncthreads();
        for (int i = tid; i < cn; i += 256) {
            uint2 p = buf[i];
            int b = __umulhi(p.y, M);
            arena[gbase[b] + (i - lbase[b])] = (p.x << 10) | (p.y - (unsigned)(b * BW));
        }
        __syncthreads();
    }
}

// ------- per-bucket padded CSR build (pad to 16; off = base | niter<<25) -------
__global__ void __launch_bounds__(1024) buildC(const unsigned* __restrict__ arena_all,
                                               const int* __restrict__ bbase,
                                               int E, int N, int BW,
                                               int* __restrict__ csr0p, int* __restrict__ csr1p,
                                               unsigned* __restrict__ offp0, unsigned* __restrict__ offp1,
                                               float* __restrict__ dinv0, float* __restrict__ dinv1) {
    __shared__ int degl[800], scn[800], cur[800];
    int list = blockIdx.x >> 7, rb = blockIdx.x & (RB - 1);
    const unsigned* arena = arena_all + (size_t)list * E;
    int* csr = list ? csr1p : csr0p;
    unsigned* offp = list ? offp1 : offp0;
    float* dinv = list ? dinv1 : dinv0;
    int base = bbase[list * (RB + 1) + rb];
    int end  = bbase[list * (RB + 1) + rb + 1];
    int csrb = base + 16 * BW * rb;
    int nbase = rb * BW;
    int nn = min(BW, N - nbase);
    if (nn <= 0) return;
    int tid = threadIdx.x;
    for (int i = tid; i < nn; i += 1024) degl[i] = 0;
    __syncthreads();
    for (int j = base + tid; j < end; j += 1024)
        atomicAdd(&degl[arena[j] & 1023u], 1);
    __syncthreads();
    int d = (tid < nn) ? degl[tid] : 0;
    int dp = d ? ((d + 15) & ~15) : 0;
    if (tid < nn) scn[tid] = dp;
    __syncthreads();
    for (int o = 1; o < nn; o <<= 1) {
        int u = (tid < nn && tid >= o) ? scn[tid - o] : 0;
        __syncthreads();
        if (tid < nn) scn[tid] += u;
        __syncthreads();
    }
    if (tid < nn) {
        int ex = scn[tid] - dp;
        cur[tid] = ex;
        offp[nbase + tid] = (unsigned)(csrb + ex) | ((unsigned)(dp >> 4) << 25);
        dinv[nbase + tid] = rsqrtf((float)(d + 1));
        for (int j = ex + d; j < ex + dp; ++j) csr[csrb + j] = N;   // pads -> zero row
    }
    __syncthreads();
    for (int j = base + tid; j < end; j += 1024) {
        unsigned p = arena[j];
        int loc = atomicAdd(&cur[p & 1023u], 1);
        csr[csrb + loc] = (int)(p >> 10);
    }
}

// ------ input projection: gh = bf16(x@W_in[t] + b_in[t]); unroll 16 ------
__global__ void input_proj(const float* __restrict__ x, const int* __restrict__ types,
                           const float* __restrict__ W_in, const float* __restrict__ b_in,
                           ushort* __restrict__ gh, int N, int F) {
    __shared__ float xs[4 * 128];
    int tid = threadIdx.x;
    int w = tid >> 6, h = tid & 63;
    int n0 = blockIdx.x * 4;
    for (int i = tid; i < 4 * F; i += 256) {
        int nn = n0 + i / F;
        xs[i] = (nn < N) ? x[(size_t)nn * F + (i % F)] : 0.0f;
    }
    __syncthreads();
    int n = n0 + w;
    if (n >= N) return;
    int t = types[n];
    const float* W = W_in + (size_t)t * F * HID;
    float acc = b_in[t * HID + h];
    const float* xr = xs + w * F;
    #pragma unroll 16
    for (int f = 0; f < F; ++f)
        acc = fmaf(xr[f], W[(size_t)f * HID + h], acc);
    gh[(size_t)n * HID + h] = f2bf(acc);
}

// weighted gather: 128B rows, 4 edges/load, 16 edges/iter, idx prefetch (r13)
__device__ __forceinline__ void gatherW(const uint2* __restrict__ GH,
                                        const float* __restrict__ dv,
                                        const int* __restrict__ csr,
                                        unsigned wword, int q, int fl, float a[4]) {
    int base = (int)(wword & 0x1FFFFFFu);
    int it = (int)(wword >> 25);
    if (it == 0) return;
    const int* cp = csr + base;
    int ia = cp[q], ib = cp[4 + q], ic = cp[8 + q], id = cp[12 + q];
    while (true) {
        uint2 va = GH[(size_t)ia * 16 + fl];
        uint2 vb = GH[(size_t)ib * 16 + fl];
        uint2 vc = GH[(size_t)ic * 16 + fl];
        uint2 vd = GH[(size_t)id * 16 + fl];
        float wa = dv[ia], wb = dv[ib], wc = dv[ic], wd = dv[id];
        --it; cp += 16;
        int na = 0, nb = 0, nc = 0, nd = 0;
        if (it > 0) { na = cp[q]; nb = cp[4 + q]; nc = cp[8 + q]; nd = cp[12 + q]; }
        addw(a, va, wa); addw(a, vb, wb); addw(a, vc, wc); addw(a, vd, wd);
        if (it == 0) break;
        ia = na; ib = nb; ic = nc; id = nd;
    }
}

// dual-node unweighted gather: two independent chains, 8 rows in flight
__device__ __forceinline__ void gatherU2(const uint2* __restrict__ GH,
                                         const int* __restrict__ csr,
                                         unsigned wA, unsigned wB,
                                         int q, int fl, float aA[4], float aB[4]) {
    int baseA = (int)(wA & 0x1FFFFFFu), itA = (int)(wA >> 25);
    int baseB = (int)(wB & 0x1FFFFFFu), itB = (int)(wB >> 25);
    const int* cpA = csr + baseA;
    const int* cpB = csr + baseB;
    int c = min(itA, itB);
    for (int i = 0; i < c; ++i) {
        int a0 = cpA[q], a1 = cpA[4 + q], a2 = cpA[8 + q], a3 = cpA[12 + q];
        int b0 = cpB[q], b1 = cpB[4 + q], b2 = cpB[8 + q], b3 = cpB[12 + q];
        uint2 vA0 = GH[(size_t)a0 * 16 + fl];
        uint2 vA1 = GH[(size_t)a1 * 16 + fl];
        uint2 vA2 = GH[(size_t)a2 * 16 + fl];
        uint2 vA3 = GH[(size_t)a3 * 16 + fl];
        uint2 vB0 = GH[(size_t)b0 * 16 + fl];
        uint2 vB1 = GH[(size_t)b1 * 16 + fl];
        uint2 vB2 = GH[(size_t)b2 * 16 + fl];
        uint2 vB3 = GH[(size_t)b3 * 16 + fl];
        addu(aA, vA0); addu(aA, vA1); addu(aA, vA2); addu(aA, vA3);
        addu(aB, vB0); addu(aB, vB1); addu(aB, vB2); addu(aB, vB3);
        cpA += 16; cpB += 16;
    }
    itA -= c; itB -= c;
    for (; itA > 0; --itA) {
        int a0 = cpA[q], a1 = cpA[4 + q], a2 = cpA[8 + q], a3 = cpA[12 + q];
        uint2 v0 = GH[(size_t)a0 * 16 + fl];
        uint2 v1 = GH[(size_t)a1 * 16 + fl];
        uint2 v2 = GH[(size_t)a2 * 16 + fl];
        uint2 v3 = GH[(size_t)a3 * 16 + fl];
        addu(aA, v0); addu(aA, v1); addu(aA, v2); addu(aA, v3);
        cpA += 16;
    }
    for (; itB > 0; --itB) {
        int b0 = cpB[q], b1 = cpB[4 + q], b2 = cpB[8 + q], b3 = cpB[12 + q];
        uint2 v0 = GH[(size_t)b0 * 16 + fl];
        uint2 v1 = GH[(size_t)b1 * 16 + fl];
        uint2 v2 = GH[(size_t)b2 * 16 + fl];
        uint2 v3 = GH[(size_t)b3 * 16 + fl];
        addu(aB, v0); addu(aB, v1); addu(aB, v2); addu(aB, v3);
        cpB += 16;
    }
}

// ------- layer 1: two weighted gathers over gh + W0/W1 matvec + max (r13) -------
__global__ void __launch_bounds__(512) gatherL1(
        const ushort* __restrict__ gh,
        const unsigned* __restrict__ offp0, const int* __restrict__ csr0p,
        const float* __restrict__ dinv0,
        const unsigned* __restrict__ offp1, const int* __restrict__ csr1p,
        const float* __restrict__ dinv1,
        const float* __restrict__ W_conv, const float* __restrict__ b_conv,
        unsigned* __restrict__ a0g, ushort* __restrict__ s1g, int N) {
    __shared__ float Ws[2 * HID * HID];        // 32 KB fp32 W0,W1
    __shared__ float l0[8][HID], l1[8][HID];
    int tid = threadIdx.x;
    for (int i = tid; i < 2 * HID * HID; i += 512) Ws[i] = W_conv[i];
    __syncthreads();
    int w = tid >> 6, lane = tid & 63;
    int q = lane >> 4, fl = lane & 15;
    int n = blockIdx.x * 8 + w;
    if (n >= N) return;
    const uint2* GH = (const uint2*)gh;
    float d0 = dinv0[n], d1 = dinv1[n];
    float a0[4] = {0, 0, 0, 0}, a1[4] = {0, 0, 0, 0};
    if (q == 0) {                              // self terms
        uint2 sv = GH[(size_t)n * 16 + fl];
        float f0 = bflo(sv.x), f1 = bfhi(sv.x), f2 = bflo(sv.y), f3 = bfhi(sv.y);
        a0[0] = f0 * d0; a0[1] = f1 * d0; a0[2] = f2 * d0; a0[3] = f3 * d0;
        a1[0] = f0 * d1; a1[1] = f1 * d1; a1[2] = f2 * d1; a1[3] = f3 * d1;
    }
    gatherW(GH, dinv0, csr0p, offp0[n], q, fl, a0);
    gatherW(GH, dinv1, csr1p, offp1[n], q, fl, a1);
    #pragma unroll
    for (int k = 0; k < 4; ++k) {
        a0[k] += __shfl_xor(a0[k], 16, 64);
        a0[k] += __shfl_xor(a0[k], 32, 64);
        a1[k] += __shfl_xor(a1[k], 16, 64);
        a1[k] += __shfl_xor(a1[k], 32, 64);
        a0[k] *= d0;
        a1[k] *= d1;
    }
    if (q == 0) {
        *(float4*)&l0[w][fl * 4] = make_float4(a0[0], a0[1], a0[2], a0[3]);
        *(float4*)&l1[w][fl * 4] = make_float4(a1[0], a1[1], a1[2], a1[3]);
        uint2 pk;
        pk.x = (unsigned)f2bf(a0[0]) | ((unsigned)f2bf(a0[1]) << 16);
        pk.y = (unsigned)f2bf(a0[2]) | ((unsigned)f2bf(a0[3]) << 16);
        ((uint2*)a0g)[(size_t)n * 16 + fl] = pk;      // agg0 bf16 for layer 2
    }
    int h = lane;
    float m0 = b_conv[h];
    float m1 = b_conv[HID + h];
    #pragma unroll 8
    for (int k = 0; k < HID; ++k) {
        m0 = fmaf(l0[w][k], Ws[k * HID + h], m0);
        m1 = fmaf(l1[w][k], Ws[HID * HID + k * HID + h], m1);
    }
    s1g[(size_t)n * HID + h] = f2bf(fmaxf(m0, m1) * d0);
}

// ------- layer 2: dual-node gather(s1g) + W2/W3c matvec + max + LN + gelu + W3 -------
__global__ void __launch_bounds__(512) gatherL2(
        const unsigned* __restrict__ a0g, const ushort* __restrict__ s1g,
        const unsigned* __restrict__ offp0, const int* __restrict__ csr0p,
        const float* __restrict__ dinv0,
        const float* __restrict__ W_conv, const float* __restrict__ b_conv,
        const float* __restrict__ W3, const float* __restrict__ b3,
        float* __restrict__ out, int N) {
    __shared__ float Ws[2 * HID * HID];        // 32 KB fp32 W2,W3c
    __shared__ float W3s[HID * 8];
    __shared__ float l2[16][HID], l3[16][HID], gs[16][HID];
    int tid = threadIdx.x;
    for (int i = tid; i < 2 * HID * HID; i += 512) Ws[i] = W_conv[2 * HID * HID + i];
    if (tid < HID * 8) W3s[tid] = W3[tid];
    __syncthreads();
    int w = tid >> 6, lane = tid & 63;
    int q = lane >> 4, fl = lane & 15;
    int nA = blockIdx.x * 16 + 2 * w;
    int nB = nA + 1;
    if (nA >= N) return;
    bool hasB = (nB < N);
    const uint2* S = (const uint2*)s1g;
    float d0A = dinv0[nA];
    float d0B = hasB ? dinv0[nB] : 0.0f;
    float aA[4] = {0, 0, 0, 0}, aB[4] = {0, 0, 0, 0};
    if (q == 0) {                              // self A; stage a0g row A
        uint2 sv = S[(size_t)nA * 16 + fl];
        aA[0] = bflo(sv.x); aA[1] = bfhi(sv.x);
        aA[2] = bflo(sv.y); aA[3] = bfhi(sv.y);
        uint2 av = ((const uint2*)a0g)[(size_t)nA * 16 + fl];
        *(float4*)&l2[2 * w][fl * 4] = make_float4(bflo(av.x), bfhi(av.x), bflo(av.y), bfhi(av.y));
    }
    if (q == 1 && hasB) {                      // self B; stage a0g row B
        uint2 sv = S[(size_t)nB * 16 + fl];
        aB[0] = bflo(sv.x); aB[1] = bfhi(sv.x);
        aB[2] = bflo(sv.y); aB[3] = bfhi(sv.y);
        uint2 av = ((const uint2*)a0g)[(size_t)nB * 16 + fl];
        *(float4*)&l2[2 * w + 1][fl * 4] = make_float4(bflo(av.x), bfhi(av.x), bflo(av.y), bfhi(av.y));
    }
    unsigned wwA = offp0[nA];
    unsigned wwB = hasB ? offp0[nB] : 0u;
    gatherU2(S, csr0p, wwA, wwB, q, fl, aA, aB);
    #pragma unroll
    for (int k = 0; k < 4; ++k) {
        aA[k] += __shfl_xor(aA[k], 16, 64);
        aA[k] += __shfl_xor(aA[k], 32, 64);
        aB[k] += __shfl_xor(aB[k], 16, 64);
        aB[k] += __shfl_xor(aB[k], 32, 64);
        aA[k] *= d0A;
        aB[k] *= d0B;
    }
    if (q == 0)
        *(float4*)&l3[2 * w][fl * 4] = make_float4(aA[0], aA[1], aA[2], aA[3]);
    if (q == 1 && hasB)
        *(float4*)&l3[2 * w + 1][fl * 4] = make_float4(aB[0], aB[1], aB[2], aB[3]);
    int h = lane;
    float m2A = b_conv[2 * HID + h], m3A = b_conv[3 * HID + h];
    float m2B = m2A, m3B = m3A;
    #pragma unroll 8
    for (int k = 0; k < HID; ++k) {
        float w2 = Ws[k * HID + h];
        float w3 = Ws[HID * HID + k * HID + h];
        m2A = fmaf(l2[2 * w][k], w2, m2A);
        m3A = fmaf(l3[2 * w][k], w3, m3A);
        m2B = fmaf(l2[2 * w + 1][k], w2, m2B);
        m3B = fmaf(l3[2 * w + 1][k], w3, m3B);
    }
    float s2A = fmaxf(m2A, m3A);
    float s2B = fmaxf(m2B, m3B);
    float sumA = s2A, sumB = s2B;
    #pragma unroll
    for (int off = 32; off; off >>= 1) {
        sumA += __shfl_xor(sumA, off, 64);
        sumB += __shfl_xor(sumB, off, 64);
    }
    float muA = sumA * (1.0f / 64.0f), muB = sumB * (1.0f / 64.0f);
    float dvA = s2A - muA, dvB = s2B - muB;
    float vA = dvA * dvA, vB = dvB * dvB;
    #pragma unroll
    for (int off = 32; off; off >>= 1) {
        vA += __shfl_xor(vA, off, 64);
        vB += __shfl_xor(vB, off, 64);
    }
    float xnA = dvA * rsqrtf(vA * (1.0f / 64.0f) + 1e-5f);
    float xnB = dvB * rsqrtf(vB * (1.0f / 64.0f) + 1e-5f);
    float gA = 0.5f * xnA * (1.0f + erff(xnA * 0.70710678118654752f));
    float gB = 0.5f * xnB * (1.0f + erff(xnB * 0.70710678118654752f));
    gs[2 * w][h] = gA;
    gs[2 * w + 1][h] = gB;
    if (h < 8) {
        float accA = b3[h], accB = b3[h];
        #pragma unroll 8
        for (int k = 0; k < HID; ++k) {
            float w3v = W3s[k * 8 + h];
            accA = fmaf(gs[2 * w][k], w3v, accA);
            accB = fmaf(gs[2 * w + 1][k], w3v, accB);
        }
        out[(size_t)nA * 8 + h] = accA;
        if (hasB) out[(size_t)nB * 8 + h] = accB;
    }
}

extern "C" void kernel_launch(void* const* d_in, const int* in_sizes, int n_in,
                              void* d_out, int out_size, void* d_ws, size_t ws_size,
                              hipStream_t stream) {
    const float* x          = (const float*)d_in[0];
    const int*   node_types = (const int*)d_in[1];
    const int*   e0         = (const int*)d_in[2];
    const int*   e1         = (const int*)d_in[3];
    const float* W_in       = (const float*)d_in[4];
    const float* b_in       = (const float*)d_in[5];
    const float* W_conv     = (const float*)d_in[6];
    const float* b_conv     = (const float*)d_in[7];
    const float* W3         = (const float*)d_in[12];
    const float* b3         = (const float*)d_in[13];
    float* out = (float*)d_out;

    int N = in_sizes[1];
    int F = in_sizes[0] / N;        // 128
    int E = in_sizes[2] / 2;        // 1.6M
    int BW = (N + RB - 1) / RB;     // 782
    unsigned M = (unsigned)(0x100000000ULL / (unsigned long long)BW) + 1u;
    size_t EP = (size_t)E + 16 * (size_t)BW * RB + 64;

    // workspace layout (u32 units)
    unsigned* ws32 = (unsigned*)d_ws;
    int*      bcnt  = (int*)ws32;                        // 2*RB
    int*      bbase = bcnt + 2 * RB;                     // 2*(RB+1)
    int*      bcur  = bbase + 2 * (RB + 1);              // 2*RB (+6 pad)
    unsigned* offp0 = (unsigned*)(bcur + 2 * RB + 6);    // N+1
    unsigned* offp1 = offp0 + (N + 1);                   // N+1
    float*    dinv0 = (float*)(offp1 + (N + 1));         // N+1
    float*    dinv1 = dinv0 + (N + 1);                   // N+1
    int*      csr0p = (int*)(dinv1 + (N + 1));           // EP
    int*      csr1p = csr0p + EP;                        // EP
    ushort*   gh    = (ushort*)(csr1p + EP);             // (N+1)*64 bf16
    ushort*   s1g   = gh + (size_t)(N + 1) * HID;        // (N+1)*64 bf16
    unsigned* a0g   = (unsigned*)(s1g + (size_t)(N + 1) * HID);  // N*32 u32
    unsigned* arena = a0g;                               // 2E u32, dead before gatherL1

    (void)hipMemsetAsync(bcnt, 0, 2 * RB * sizeof(int), stream);
    zeroRow<<<1, 64, 0, stream>>>((unsigned*)(gh + (size_t)N * HID),
                                  (unsigned*)(s1g + (size_t)N * HID), dinv0, dinv1, N);
    histA<<<1024, 256, 0, stream>>>(e0 + E, e1 + E, E, M, bcnt);
    scanA<<<1, 256, 0, stream>>>(bcnt, bbase, bcur);
    partB<<<256, 256, 0, stream>>>(e0, e1, E, BW, M, bcur, arena);
    buildC<<<2 * RB, 1024, 0, stream>>>(arena, bbase, E, N, BW,
                                        csr0p, csr1p, offp0, offp1, dinv0, dinv1);
    input_proj<<<(N + 3) / 4, 256, 0, stream>>>(x, node_types, W_in, b_in, gh, N, F);
    gatherL1<<<(N + 7) / 8, 512, 0, stream>>>(gh, offp0, csr0p, dinv0, offp1, csr1p, dinv1,
                                              W_conv, b_conv, a0g, s1g, N);
    gatherL2<<<(N + 15) / 16, 512, 0, stream>>>(a0g, s1g, offp0, csr0p, dinv0,
                                                W_conv, b_conv, W3, b3, out, N);
}